// Round 9
// baseline (172.547 us; speedup 1.0000x reference)
//
#include <hip/hip_runtime.h>

typedef unsigned short u16;
typedef unsigned int u32;
typedef __bf16 bf16x8 __attribute__((ext_vector_type(8)));
typedef float f32x4 __attribute__((ext_vector_type(4)));

#define MFMA16(a, b, c) __builtin_amdgcn_mfma_f32_16x16x32_bf16(a, b, c, 0, 0, 0)
#define LOG2E 1.4426950408889634f

__device__ __forceinline__ u16 f2bf(float f) {
  u32 u = __float_as_uint(f);
  u += 0x7FFFu + ((u >> 16) & 1u);   // RNE to bf16
  return (u16)(u >> 16);
}

__device__ __forceinline__ void gld16(u16* lds, const u16* g) {
  __builtin_amdgcn_global_load_lds((const __attribute__((address_space(1))) void*)g,
                                   (__attribute__((address_space(3))) void*)lds,
                                   16, 0, 0);
}

// Exact integer replication of T5 bucketing (bidirectional, 32 buckets, max_dist 128).
__device__ __forceinline__ int t5_bucket(int rp) {
  int ret = rp > 0 ? 16 : 0;
  int a = rp < 0 ? -rp : rp;
  int b;
  if      (a <  8) b = a;
  else if (a < 12) b = 8;
  else if (a < 16) b = 9;
  else if (a < 23) b = 10;
  else if (a < 32) b = 11;
  else if (a < 46) b = 12;
  else if (a < 64) b = 13;
  else if (a < 91) b = 14;
  else             b = 15;
  return ret + b;
}

// ---------------- fused prep, grid 1024: blocks 0..511 X cvt, 512..1023 W cvt ----
__global__ __launch_bounds__(256) void prep(const float4* __restrict__ X, ushort4* __restrict__ Xb,
                                            const float* __restrict__ w0, const float* __restrict__ w1,
                                            const float* __restrict__ w2, const float* __restrict__ w3,
                                            u16* __restrict__ out) {
  int bid = blockIdx.x;
  if (bid < 512) {
#pragma unroll
    for (int i = 0; i < 8; i++) {
      int g = bid * 2048 + i * 256 + threadIdx.x;
      float4 v = X[g];
      ushort4 o;
      o.x = f2bf(v.x); o.y = f2bf(v.y); o.z = f2bf(v.z); o.w = f2bf(v.w);
      Xb[g] = o;
    }
    return;
  }
  bid -= 512;
  __shared__ __align__(16) u16 tb[64 * 68];
  const int col = threadIdx.x & 63;
  const int rowo = threadIdx.x >> 6;
#pragma unroll 1
  for (int t2 = 0; t2 < 2; t2++) {
    const int tile = bid * 2 + t2;
    const int z = tile >> 8, t = tile & 255;
    const float* W = (z == 0) ? w0 : (z == 1) ? w1 : (z == 2) ? w2 : w3;
    u16* O = out + z * 1048576;
    const int n0 = (t & 15) * 64, k0 = (t >> 4) * 64;
#pragma unroll
    for (int r = 0; r < 16; r++) {
      int kl = r * 4 + rowo;
      tb[col * 68 + kl] = f2bf(W[(k0 + kl) * 1024 + n0 + col]);
    }
    __syncthreads();
#pragma unroll
    for (int r = 0; r < 16; r++) {
      int nl = r * 4 + rowo;
      O[(n0 + nl) * 1024 + k0 + col] = tb[nl * 68 + col];
    }
    __syncthreads();
  }
}

// -------- Q|K GEMM: 512 threads, 128m x 256n tiles, BK=32, 3-stage async pipeline --------
// Traffic-reduction round: (Tm+Tn)/(Tm*Tn) improves 1.5x vs 128x128 -> 201 MB staged for Q+K.
// Grid 256 = exactly 1 block/CU; n-tiles are z-pure (256 | 1024); wave-tile stays 64x64 (64 acc regs).
__global__ __launch_bounds__(512) void qk512(const u16* __restrict__ A,
                                             const u16* __restrict__ Wt,
                                             u16* __restrict__ outp) {
  __shared__ __align__(16) u16 smem[36864];   // 3 stages x (A 4096 + B 8192) u16 = 72 KB; epilogue retile 128x264 (67.5 KB)
  const int tid = threadIdx.x, lane = tid & 63, wave = tid >> 6;
  const int l15 = lane & 15, quad = (lane >> 4) & 3;
  const int wm = (wave >> 2) * 64, wn = (wave & 3) * 64;
  const int id = blockIdx.x;
  const int nq = id & 7, m = id >> 3;   // xcd = id%8 = nq -> 512 KB B-slab L2-resident per XCD
  const int m0 = m * 128, n0 = nq * 256;
  const int z = nq >> 2;                // 0:Q (log2e-scaled), 1:K
  const u16* Ab = A + m0 * 1024;
  const u16* Bb = Wt + n0 * 1024;       // Wq^T,Wk^T contiguous: col n lives at Wt + n*1024

  // staging coords (BK=32: row has 4 16B chunks, chunk j holds src chunk j^((row>>1)&3))
  const int ar = tid >> 2;
  const int aoff = ar * 1024 + (((tid & 3) ^ ((ar >> 1) & 3)) * 8);
  int boff[2], bdst[2];
#pragma unroll
  for (int r = 0; r < 2; r++) {
    int cc = r * 512 + tid;
    int row = cc >> 2;
    boff[r] = row * 1024 + (((cc & 3) ^ ((row >> 1) & 3)) * 8);
    bdst[r] = 4096 + cc * 8;
  }

  f32x4 acc[4][4];
  const f32x4 vz = {0.f, 0.f, 0.f, 0.f};
#pragma unroll
  for (int i = 0; i < 4; i++)
#pragma unroll
    for (int j = 0; j < 4; j++) acc[i][j] = vz;

  const int sk = (l15 >> 1) & 3;

  // prologue: tiles 0,1 into stages 0,1 (3 gld16 per thread per tile)
#pragma unroll
  for (int s = 0; s < 2; s++) {
    u16* st = smem + s * 12288;
    const int ka = s * 32;
    gld16(st + tid * 8, Ab + ka + aoff);
    gld16(st + bdst[0], Bb + ka + boff[0]);
    gld16(st + bdst[1], Bb + ka + boff[1]);
  }

  int cs = 0, ls = 2;
#pragma unroll 1
  for (int kt = 0; kt < 32; kt++) {
    if (kt < 30) {
      u16* dst = smem + ls * 12288;
      const int ka = (kt + 2) * 32;
      gld16(dst + tid * 8, Ab + ka + aoff);
      gld16(dst + bdst[0], Bb + ka + boff[0]);
      gld16(dst + bdst[1], Bb + ka + boff[1]);
      asm volatile("s_waitcnt vmcnt(6)\n\ts_barrier" ::: "memory");
    } else if (kt == 30) {
      asm volatile("s_waitcnt vmcnt(3)\n\ts_barrier" ::: "memory");
    } else {
      asm volatile("s_waitcnt vmcnt(0)\n\ts_barrier" ::: "memory");
    }
    u16* st = smem + cs * 12288;
    bf16x8 af[4], bg[4];
#pragma unroll
    for (int mt = 0; mt < 4; mt++)
      af[mt] = *(const bf16x8*)(st + (wm + mt * 16 + l15) * 32 + ((quad ^ sk) * 8));
#pragma unroll
    for (int nt = 0; nt < 4; nt++)
      bg[nt] = *(const bf16x8*)(st + 4096 + (wn + nt * 16 + l15) * 32 + ((quad ^ sk) * 8));
#pragma unroll
    for (int mt = 0; mt < 4; mt++)
#pragma unroll
      for (int nt = 0; nt < 4; nt++)
        acc[mt][nt] = MFMA16(af[mt], bg[nt], acc[mt][nt]);
    asm volatile("s_barrier" ::: "memory");
    cs = (cs == 2) ? 0 : cs + 1;
    ls = (ls == 2) ? 0 : ls + 1;
  }
  __syncthreads();

  // epilogue: retile [m][n] stride 264, then 16B coalesced stores to Q/K[b,h,s,dk]
  const float scl = (z == 0) ? LOG2E : 1.0f;
#pragma unroll
  for (int mt = 0; mt < 4; mt++)
#pragma unroll
    for (int nt = 0; nt < 4; nt++) {
      int rowb = wm + mt * 16 + quad * 4;
      int colb = wn + nt * 16 + l15;
#pragma unroll
      for (int reg = 0; reg < 4; reg++)
        smem[(rowb + reg) * 264 + colb] = f2bf(acc[mt][nt][reg] * scl);
    }
  __syncthreads();
  u16* O = outp + z * 4194304;
  const int b = m0 >> 10, sbase = m0 & 1023;
#pragma unroll
  for (int p = 0; p < 8; p++) {
    int g = p * 512 + tid;
    int ml = g >> 5, c = g & 31;
    uint4 v = *(const uint4*)(smem + ml * 264 + c * 8);
    int col10 = (n0 & 1023) + c * 8;
    int hh = col10 >> 6, dk = col10 & 63;
    *(uint4*)(O + (b * 16 + hh) * 65536 + (sbase + ml) * 64 + dk) = v;
  }
}

// -------- V GEMM: 128x128 tiles, BK=32, 3-stage, Vt[b,h,dk,s] transpose epilogue --------
__global__ __launch_bounds__(256) void gemmv(const u16* __restrict__ A,
                                             const u16* __restrict__ Bt,
                                             u16* __restrict__ Vt) {
  __shared__ __align__(16) u16 smem[24576];   // 3 stages x 8192 u16; epilogue 128x136 retile
  const int tid = threadIdx.x, lane = tid & 63, wave = tid >> 6;
  const int l15 = lane & 15, quad = lane >> 4;
  const int wm = (wave >> 1) * 64, wn = (wave & 1) * 64;
  const int id = blockIdx.x + blockIdx.y * 8;
  const int n = id & 7, m = id >> 3;    // xcd = n -> 256 KB B-slab per XCD
  const int m0 = m * 128, n0 = n * 128;
  const u16* Ab = A + m0 * 1024;
  const u16* Bb = Bt + n0 * 1024;

  int cc0 = tid, cc1 = 256 + tid;
  int row0 = cc0 >> 2, row1 = cc1 >> 2;
  int aoff0 = row0 * 1024 + (((cc0 & 3) ^ ((row0 >> 1) & 3)) * 8);
  int aoff1 = row1 * 1024 + (((cc1 & 3) ^ ((row1 >> 1) & 3)) * 8);

  f32x4 acc[4][4];
  const f32x4 vz = {0.f, 0.f, 0.f, 0.f};
#pragma unroll
  for (int i = 0; i < 4; i++)
#pragma unroll
    for (int j = 0; j < 4; j++) acc[i][j] = vz;

  const int sk = (l15 >> 1) & 3;

#pragma unroll
  for (int s = 0; s < 2; s++) {
    u16* st = smem + s * 8192;
    const int ka = s * 32;
    gld16(st + cc0 * 8, Ab + ka + aoff0);
    gld16(st + cc1 * 8, Ab + ka + aoff1);
    gld16(st + 4096 + cc0 * 8, Bb + ka + aoff0);
    gld16(st + 4096 + cc1 * 8, Bb + ka + aoff1);
  }

  int cs = 0, ls = 2;
#pragma unroll 1
  for (int kt = 0; kt < 32; kt++) {
    if (kt < 30) {
      u16* dst = smem + ls * 8192;
      const int ka = (kt + 2) * 32;
      gld16(dst + cc0 * 8, Ab + ka + aoff0);
      gld16(dst + cc1 * 8, Ab + ka + aoff1);
      gld16(dst + 4096 + cc0 * 8, Bb + ka + aoff0);
      gld16(dst + 4096 + cc1 * 8, Bb + ka + aoff1);
      asm volatile("s_waitcnt vmcnt(8)\n\ts_barrier" ::: "memory");
    } else if (kt == 30) {
      asm volatile("s_waitcnt vmcnt(4)\n\ts_barrier" ::: "memory");
    } else {
      asm volatile("s_waitcnt vmcnt(0)\n\ts_barrier" ::: "memory");
    }
    u16* st = smem + cs * 8192;
    bf16x8 af[4], bg[4];
#pragma unroll
    for (int mt = 0; mt < 4; mt++)
      af[mt] = *(const bf16x8*)(st + (wm + mt * 16 + l15) * 32 + ((quad ^ sk) * 8));
#pragma unroll
    for (int nt = 0; nt < 4; nt++)
      bg[nt] = *(const bf16x8*)(st + 4096 + (wn + nt * 16 + l15) * 32 + ((quad ^ sk) * 8));
#pragma unroll
    for (int mt = 0; mt < 4; mt++)
#pragma unroll
      for (int nt = 0; nt < 4; nt++)
        acc[mt][nt] = MFMA16(af[mt], bg[nt], acc[mt][nt]);
    asm volatile("s_barrier" ::: "memory");
    cs = (cs == 2) ? 0 : cs + 1;
    ls = (ls == 2) ? 0 : ls + 1;
  }
  __syncthreads();

  // transpose in LDS (col-major stride 136) then 16B coalesced stores to Vt[b,h,dk,s]
#pragma unroll
  for (int mt = 0; mt < 4; mt++)
#pragma unroll
    for (int nt = 0; nt < 4; nt++) {
      int col = wn + nt * 16 + l15;
      int rowb = wm + mt * 16 + quad * 4;
      uint2 p;
      p.x = (u32)f2bf(acc[mt][nt][0]) | ((u32)f2bf(acc[mt][nt][1]) << 16);
      p.y = (u32)f2bf(acc[mt][nt][2]) | ((u32)f2bf(acc[mt][nt][3]) << 16);
      *(uint2*)(smem + col * 136 + rowb) = p;
    }
  __syncthreads();
  const int b = m0 >> 10, sbase = m0 & 1023;
#pragma unroll
  for (int p = 0; p < 8; p++) {
    int g = p * 256 + tid;
    int col = g >> 4, chunk = g & 15;
    uint4 v = *(const uint4*)(smem + col * 136 + chunk * 8);
    int nn = n0 + col, hh = nn >> 6, dk = nn & 63;
    *(uint4*)(Vt + ((b * 16 + hh) * 64 + dk) * 1024 + sbase + chunk * 8) = v;
  }
}

// ------- flash attention: (b,h) x 128 q-rows; 2-stage K/V async double-buffer -------
__global__ __launch_bounds__(256) void attn(const u16* __restrict__ Q, const u16* __restrict__ K,
                                            const u16* __restrict__ V, const float* __restrict__ emb,
                                            u16* __restrict__ ctx) {
  __shared__ __align__(16) u16 sKV[2 * 8192];   // stage: sK(4096 u16) + sV(4096 u16)
  __shared__ __align__(16) u16 sP[128 * 72];    // P [qrow][key], stride 72
  __shared__ __align__(16) float4 bt4[1156];    // replicated bias*log2e
  const int tid = threadIdx.x, lane = tid & 63, wave = tid >> 6;
  const int l15 = lane & 15, quad = lane >> 4;
  const int bh = blockIdx.x, qt = blockIdx.y;
  const int h = bh & 15, b = bh >> 4;
  const u16* Qp = Q + bh * 65536 + qt * 8192;
  const u16* Kp = K + bh * 65536;
  const u16* Vp = V + bh * 65536;
  const int sx = l15 & 7;

  int koff[2], voff[2], cbs[2];
#pragma unroll
  for (int r = 0; r < 2; r++) {
    int cb = r * 256 + wave * 64;
    int cc = cb + lane;
    int row = cc >> 3, c8 = (cc & 7) ^ (row & 7);
    koff[r] = row * 64 + c8 * 8;
    voff[r] = row * 1024 + c8 * 8;
    cbs[r] = cb * 8;
  }

  bf16x8 aq[2][2];
#pragma unroll
  for (int u = 0; u < 2; u++)
#pragma unroll
    for (int kk = 0; kk < 2; kk++)
      aq[u][kk] = *(const bf16x8*)(Qp + (wave * 32 + u * 16 + l15) * 64 + kk * 32 + quad * 8);

#pragma unroll
  for (int r = 0; r < 2; r++) {
    gld16(sKV + cbs[r], Kp + koff[r]);
    gld16(sKV + 4096 + cbs[r], Vp + voff[r]);
  }

  for (int i = tid; i < 1156; i += 256) {
    int rp0 = i - 127 - qt * 128;
    float4 v;
    v.x = emb[t5_bucket(rp0)     * 16 + h] * LOG2E;
    v.y = emb[t5_bucket(rp0 + 1) * 16 + h] * LOG2E;
    v.z = emb[t5_bucket(rp0 + 2) * 16 + h] * LOG2E;
    v.w = emb[t5_bucket(rp0 + 3) * 16 + h] * LOG2E;
    bt4[i] = v;
  }
  const float bias_pos = emb[31 * 16 + h] * LOG2E;  // rp >= 91
  const float bias_neg = emb[15 * 16 + h] * LOG2E;  // rp <= -91

  float2 ls2[2] = {{0.f, 0.f}, {0.f, 0.f}};
  f32x4 oc[2][4];
  const f32x4 vzero = {0.f, 0.f, 0.f, 0.f};
#pragma unroll
  for (int u = 0; u < 2; u++)
#pragma unroll
    for (int nt = 0; nt < 4; nt++) oc[u][nt] = vzero;

  __syncthreads();   // bt4 ready (also drains tile-0 loads — startup only)

#pragma unroll 1
  for (int j = 0; j < 16; j++) {
    u16* st = sKV + (j & 1) * 8192;
    if (j < 15) {
      u16* dst = sKV + ((j + 1) & 1) * 8192;
      const u16* Kj1 = Kp + (j + 1) * 4096;
      const u16* Vj1 = Vp + (j + 1) * 64;
#pragma unroll
      for (int r = 0; r < 2; r++) {
        gld16(dst + cbs[r], Kj1 + koff[r]);
        gld16(dst + 4096 + cbs[r], Vj1 + voff[r]);
      }
      asm volatile("s_waitcnt vmcnt(4)\n\ts_barrier" ::: "memory");
    } else {
      asm volatile("s_waitcnt vmcnt(0)\n\ts_barrier" ::: "memory");
    }

    f32x4 sc[4][2];
    const int rp_min = j * 64 - qt * 128 - 127;
    const int rp_max = j * 64 + 63 - qt * 128;
    if (rp_min >= 91) {
#pragma unroll
      for (int mt = 0; mt < 4; mt++)
#pragma unroll
        for (int u = 0; u < 2; u++) { sc[mt][u][0] = bias_pos; sc[mt][u][1] = bias_pos; sc[mt][u][2] = bias_pos; sc[mt][u][3] = bias_pos; }
    } else if (rp_max <= -91) {
#pragma unroll
      for (int mt = 0; mt < 4; mt++)
#pragma unroll
        for (int u = 0; u < 2; u++) { sc[mt][u][0] = bias_neg; sc[mt][u][1] = bias_neg; sc[mt][u][2] = bias_neg; sc[mt][u][3] = bias_neg; }
    } else {
#pragma unroll
      for (int mt = 0; mt < 4; mt++)
#pragma unroll
        for (int u = 0; u < 2; u++) {
          int idx = j * 64 + mt * 16 + quad * 4 - wave * 32 - u * 16 - l15 + 127;
          float4 bv4 = bt4[idx];
          sc[mt][u][0] = bv4.x; sc[mt][u][1] = bv4.y; sc[mt][u][2] = bv4.z; sc[mt][u][3] = bv4.w;
        }
    }
#pragma unroll
    for (int kk = 0; kk < 2; kk++) {
      bf16x8 ak[4];
      int g8 = kk * 4 + quad;
#pragma unroll
      for (int mt = 0; mt < 4; mt++)
        ak[mt] = *(const bf16x8*)(st + (mt * 16 + l15) * 64 + (g8 ^ sx) * 8);
#pragma unroll
      for (int mt = 0; mt < 4; mt++)
#pragma unroll
        for (int u = 0; u < 2; u++)
          sc[mt][u] = MFMA16(ak[mt], aq[u][kk], sc[mt][u]);
    }

#pragma unroll
    for (int u = 0; u < 2; u++) {
      const int prow = wave * 32 + u * 16 + l15;
#pragma unroll
      for (int mt = 0; mt < 4; mt++) {
        u32 b0 = __float_as_uint(__builtin_amdgcn_exp2f(sc[mt][u][0]));
        u32 b1 = __float_as_uint(__builtin_amdgcn_exp2f(sc[mt][u][1]));
        u32 b2 = __float_as_uint(__builtin_amdgcn_exp2f(sc[mt][u][2]));
        u32 b3 = __float_as_uint(__builtin_amdgcn_exp2f(sc[mt][u][3]));
        u32 t0 = b0 & 0xFFFF0000u, t1 = b1 & 0xFFFF0000u;
        u32 t2 = b2 & 0xFFFF0000u, t3 = b3 & 0xFFFF0000u;
        ls2[u].x += __uint_as_float(t0) + __uint_as_float(t2);
        ls2[u].y += __uint_as_float(t1) + __uint_as_float(t3);
        uint2 pk;
        pk.x = (t0 >> 16) | t1;
        pk.y = (t2 >> 16) | t3;
        *(uint2*)(sP + prow * 72 + mt * 16 + quad * 4) = pk;
      }
    }
    asm volatile("s_waitcnt lgkmcnt(0)" ::: "memory");   // wave-private P write->read

#pragma unroll
    for (int kk = 0; kk < 2; kk++) {
      bf16x8 ap[2];
      int g8 = kk * 4 + quad;
#pragma unroll
      for (int u = 0; u < 2; u++)
        ap[u] = *(const bf16x8*)(sP + (wave * 32 + u * 16 + l15) * 72 + kk * 32 + quad * 8);
#pragma unroll
      for (int nt = 0; nt < 4; nt++) {
        bf16x8 bv = *(const bf16x8*)(st + 4096 + (nt * 16 + l15) * 64 + (g8 ^ sx) * 8);
#pragma unroll
        for (int u = 0; u < 2; u++)
          oc[u][nt] = MFMA16(ap[u], bv, oc[u][nt]);
      }
    }
    asm volatile("s_barrier" ::: "memory");
  }

  float lsum[2];
#pragma unroll
  for (int u = 0; u < 2; u++) {
    lsum[u] = ls2[u].x + ls2[u].y;
    lsum[u] += __shfl_xor(lsum[u], 16, 64);
    lsum[u] += __shfl_xor(lsum[u], 32, 64);
  }
  float linv[2][4];
#pragma unroll
  for (int u = 0; u < 2; u++)
#pragma unroll
    for (int reg = 0; reg < 4; reg++)
      linv[u][reg] = __builtin_amdgcn_rcpf(__shfl(lsum[u], quad * 4 + reg, 64));

  u16* cb2 = ctx + b * 1048576 + (qt * 128 + wave * 32) * 1024 + h * 64;
#pragma unroll
  for (int u = 0; u < 2; u++)
#pragma unroll
    for (int nt = 0; nt < 4; nt++)
#pragma unroll
      for (int reg = 0; reg < 4; reg++)
        cb2[(u * 16 + quad * 4 + reg) * 1024 + nt * 16 + l15] = f2bf(oc[u][nt][reg] * linv[u][reg]);
}

// -------- out-proj GEMM: 128x128 tiles (grid 256 = 1/CU), BK=64, 3-stage, fp32 out --------
__global__ __launch_bounds__(256) void gemm_o(const u16* __restrict__ A,
                                              const u16* __restrict__ Bt,
                                              float* __restrict__ O) {
  __shared__ __align__(16) u16 smem[49152];   // 3 stages x (A 8192 + B 8192) u16 = 96 KB
  const int tid = threadIdx.x, lane = tid & 63, wave = tid >> 6;
  const int l15 = lane & 15, quad = lane >> 4;
  const int wm = (wave >> 1) * 64, wn = (wave & 1) * 64;
  const int id = blockIdx.x + blockIdx.y * 8;
  const int n = id & 7, m = id >> 3;    // xcd = n -> 256 KB Wo-slab per XCD
  const int m0 = m * 128, n0 = n * 128;
  const u16* Ab = A + m0 * 1024;
  const u16* Bb = Bt + n0 * 1024;

  int soff[4], sdst[4];
#pragma unroll
  for (int r = 0; r < 4; r++) {
    int cc = r * 256 + tid;
    int row = cc >> 3;
    soff[r] = row * 1024 + (((cc & 7) ^ (row & 7)) * 8);
    sdst[r] = cc * 8;
  }

  f32x4 acc[4][4];
  const f32x4 vz = {0.f, 0.f, 0.f, 0.f};
#pragma unroll
  for (int i = 0; i < 4; i++)
#pragma unroll
    for (int j = 0; j < 4; j++) acc[i][j] = vz;

  const int sx = l15 & 7;

#pragma unroll
  for (int s = 0; s < 2; s++) {
    u16* st = smem + s * 16384;
    const int ka = s * 64;
#pragma unroll
    for (int r = 0; r < 4; r++) {
      gld16(st + sdst[r], Ab + ka + soff[r]);
      gld16(st + 8192 + sdst[r], Bb + ka + soff[r]);
    }
  }

  int cs = 0, ls = 2;
#pragma unroll 1
  for (int kt = 0; kt < 16; kt++) {
    if (kt < 14) {
      u16* dst = smem + ls * 16384;
      const int ka = (kt + 2) * 64;
#pragma unroll
      for (int r = 0; r < 4; r++) {
        gld16(dst + sdst[r], Ab + ka + soff[r]);
        gld16(dst + 8192 + sdst[r], Bb + ka + soff[r]);
      }
      asm volatile("s_waitcnt vmcnt(16)\n\ts_barrier" ::: "memory");
    } else if (kt == 14) {
      asm volatile("s_waitcnt vmcnt(8)\n\ts_barrier" ::: "memory");
    } else {
      asm volatile("s_waitcnt vmcnt(0)\n\ts_barrier" ::: "memory");
    }
    u16* st = smem + cs * 16384;
#pragma unroll
    for (int kk = 0; kk < 2; kk++) {
      bf16x8 af[4], bg[4];
      int g8 = kk * 4 + quad;
#pragma unroll
      for (int mt = 0; mt < 4; mt++)
        af[mt] = *(const bf16x8*)(st + (wm + mt * 16 + l15) * 64 + ((g8 ^ sx) * 8));
#pragma unroll
      for (int nt = 0; nt < 4; nt++)
        bg[nt] = *(const bf16x8*)(st + 8192 + (wn + nt * 16 + l15) * 64 + ((g8 ^ sx) * 8));
#pragma unroll
      for (int mt = 0; mt < 4; mt++)
#pragma unroll
        for (int nt = 0; nt < 4; nt++)
          acc[mt][nt] = MFMA16(af[mt], bg[nt], acc[mt][nt]);
    }
    asm volatile("s_barrier" ::: "memory");
    cs = (cs == 2) ? 0 : cs + 1;
    ls = (ls == 2) ? 0 : ls + 1;
  }

#pragma unroll
  for (int mt = 0; mt < 4; mt++)
#pragma unroll
    for (int nt = 0; nt < 4; nt++)
#pragma unroll
      for (int reg = 0; reg < 4; reg++) {
        int row = m0 + wm + mt * 16 + quad * 4 + reg;
        int col = n0 + wn + nt * 16 + l15;
        O[row * 1024 + col] = acc[mt][nt][reg];
      }
}

extern "C" void kernel_launch(void* const* d_in, const int* in_sizes, int n_in,
                              void* d_out, int out_size, void* d_ws, size_t ws_size,
                              hipStream_t stream) {
  (void)in_sizes; (void)n_in; (void)out_size; (void)ws_size;
  const float* X   = (const float*)d_in[0];
  const float* Wq  = (const float*)d_in[1];
  const float* Wk  = (const float*)d_in[2];
  const float* Wv  = (const float*)d_in[3];
  const float* Wo  = (const float*)d_in[4];
  const float* emb = (const float*)d_in[5];

  char* ws = (char*)d_ws;
  u16* Xb  = (u16*)(ws);                              // 8 MB: X bf16 [4096][1024]
  u16* Wt  = (u16*)(ws + (8u  << 20));                // 8 MB: Wq^T,Wk^T,Wv^T,Wo^T bf16
  u16* Qb  = (u16*)(ws + (16u << 20));                // 8+8+8 MB: Q(log2e-scaled), K, Vt
  u16* Ctx = (u16*)(ws + (40u << 20));                // 8 MB: attention output bf16

  prep<<<1024, 256, 0, stream>>>((const float4*)X, (ushort4*)Xb, Wq, Wk, Wv, Wo, Wt);
  qk512<<<256, 512, 0, stream>>>(Xb, Wt, Qb);
  gemmv<<<dim3(8, 32), 256, 0, stream>>>(Xb, Wt + 2 * 1048576, Qb + 2 * 4194304);
  attn<<<dim3(64, 8), 256, 0, stream>>>(Qb, Qb + 4194304, Qb + 2 * 4194304, emb, Ctx);
  gemm_o<<<dim3(8, 32), 256, 0, stream>>>(Ctx, Wt + 3 * 1048576, (float*)d_out);
}

// Round 10
// 163.392 us; speedup vs baseline: 1.0560x; 1.0560x over previous
//
#include <hip/hip_runtime.h>

typedef unsigned short u16;
typedef unsigned int u32;
typedef __bf16 bf16x8 __attribute__((ext_vector_type(8)));
typedef float f32x4 __attribute__((ext_vector_type(4)));

#define MFMA16(a, b, c) __builtin_amdgcn_mfma_f32_16x16x32_bf16(a, b, c, 0, 0, 0)
#define LOG2E 1.4426950408889634f

__device__ __forceinline__ u16 f2bf(float f) {
  u32 u = __float_as_uint(f);
  u += 0x7FFFu + ((u >> 16) & 1u);   // RNE to bf16
  return (u16)(u >> 16);
}

__device__ __forceinline__ void gld16(u16* lds, const u16* g) {
  __builtin_amdgcn_global_load_lds((const __attribute__((address_space(1))) void*)g,
                                   (__attribute__((address_space(3))) void*)lds,
                                   16, 0, 0);
}

// Exact integer replication of T5 bucketing (bidirectional, 32 buckets, max_dist 128).
__device__ __forceinline__ int t5_bucket(int rp) {
  int ret = rp > 0 ? 16 : 0;
  int a = rp < 0 ? -rp : rp;
  int b;
  if      (a <  8) b = a;
  else if (a < 12) b = 8;
  else if (a < 16) b = 9;
  else if (a < 23) b = 10;
  else if (a < 32) b = 11;
  else if (a < 46) b = 12;
  else if (a < 64) b = 13;
  else if (a < 91) b = 14;
  else             b = 15;
  return ret + b;
}

// ---------------- fused prep, grid 1024: blocks 0..511 X cvt, 512..1023 W cvt ----
__global__ __launch_bounds__(256) void prep(const float4* __restrict__ X, ushort4* __restrict__ Xb,
                                            const float* __restrict__ w0, const float* __restrict__ w1,
                                            const float* __restrict__ w2, const float* __restrict__ w3,
                                            u16* __restrict__ out) {
  int bid = blockIdx.x;
  if (bid < 512) {
#pragma unroll
    for (int i = 0; i < 8; i++) {
      int g = bid * 2048 + i * 256 + threadIdx.x;
      float4 v = X[g];
      ushort4 o;
      o.x = f2bf(v.x); o.y = f2bf(v.y); o.z = f2bf(v.z); o.w = f2bf(v.w);
      Xb[g] = o;
    }
    return;
  }
  bid -= 512;
  __shared__ __align__(16) u16 tb[64 * 68];
  const int col = threadIdx.x & 63;
  const int rowo = threadIdx.x >> 6;
#pragma unroll 1
  for (int t2 = 0; t2 < 2; t2++) {
    const int tile = bid * 2 + t2;
    const int z = tile >> 8, t = tile & 255;
    const float* W = (z == 0) ? w0 : (z == 1) ? w1 : (z == 2) ? w2 : w3;
    u16* O = out + z * 1048576;
    const int n0 = (t & 15) * 64, k0 = (t >> 4) * 64;
#pragma unroll
    for (int r = 0; r < 16; r++) {
      int kl = r * 4 + rowo;
      tb[col * 68 + kl] = f2bf(W[(k0 + kl) * 1024 + n0 + col]);
    }
    __syncthreads();
#pragma unroll
    for (int r = 0; r < 16; r++) {
      int nl = r * 4 + rowo;
      O[(n0 + nl) * 1024 + k0 + col] = tb[nl * 68 + col];
    }
    __syncthreads();
  }
}

// -------- QKV GEMM: 128x128 tiles, BK=32, 3-stage async-LDS pipeline, raw barriers --------
// Best measured config (R8, 164.0 us total). Depth-2 prefetch, vmcnt(8) steady state.
__global__ __launch_bounds__(256) void gemm128(const u16* __restrict__ A,
                                               const u16* __restrict__ BtBase,
                                               u16* __restrict__ outp) {
  __shared__ __align__(16) u16 smem[24576];   // 3 stages x 8192 u16; epilogue retile reuses
  const int tid = threadIdx.x, lane = tid & 63, wave = tid >> 6;
  const int l15 = lane & 15, quad = lane >> 4;
  const int wm = (wave >> 1) * 64, wn = (wave & 1) * 64;

  const int id = blockIdx.x + blockIdx.y * 24;
  const int xcd = id & 7, jj = id >> 3;
  const int nz = (jj % 12) + (xcd & 1) * 12;
  const int ymb = (jj / 12) + (xcd >> 1) * 8;
  const int n = nz / 3, z = nz % 3;
  const int m0 = ymb * 128, n0 = n * 128;
  const u16* Ab = A + m0 * 1024;
  const u16* Bb = BtBase + z * 1048576 + n0 * 1024;

  int cc0 = tid, cc1 = 256 + tid;
  int row0 = cc0 >> 2, row1 = cc1 >> 2;
  int aoff0 = row0 * 1024 + (((cc0 & 3) ^ ((row0 >> 1) & 3)) * 8);
  int aoff1 = row1 * 1024 + (((cc1 & 3) ^ ((row1 >> 1) & 3)) * 8);

  f32x4 acc[4][4];
  const f32x4 vz = {0.f, 0.f, 0.f, 0.f};
#pragma unroll
  for (int i = 0; i < 4; i++)
#pragma unroll
    for (int j = 0; j < 4; j++) acc[i][j] = vz;

  const int sk = (l15 >> 1) & 3;

  {
    gld16(smem + cc0 * 8, Ab + aoff0);
    gld16(smem + cc1 * 8, Ab + aoff1);
    gld16(smem + 4096 + cc0 * 8, Bb + aoff0);
    gld16(smem + 4096 + cc1 * 8, Bb + aoff1);
    gld16(smem + 8192 + cc0 * 8, Ab + 32 + aoff0);
    gld16(smem + 8192 + cc1 * 8, Ab + 32 + aoff1);
    gld16(smem + 12288 + cc0 * 8, Bb + 32 + aoff0);
    gld16(smem + 12288 + cc1 * 8, Bb + 32 + aoff1);
  }

  int cs = 0, ls = 2;
#pragma unroll 1
  for (int kt = 0; kt < 32; kt++) {
    if (kt < 30) {
      u16* dst = smem + ls * 8192;
      const int ka = (kt + 2) * 32;
      gld16(dst + cc0 * 8, Ab + ka + aoff0);
      gld16(dst + cc1 * 8, Ab + ka + aoff1);
      gld16(dst + 4096 + cc0 * 8, Bb + ka + aoff0);
      gld16(dst + 4096 + cc1 * 8, Bb + ka + aoff1);
      asm volatile("s_waitcnt vmcnt(8)\n\ts_barrier" ::: "memory");
    } else if (kt == 30) {
      asm volatile("s_waitcnt vmcnt(4)\n\ts_barrier" ::: "memory");
    } else {
      asm volatile("s_waitcnt vmcnt(0)\n\ts_barrier" ::: "memory");
    }
    u16* st = smem + cs * 8192;
    bf16x8 af[4], bg[4];
#pragma unroll
    for (int mt = 0; mt < 4; mt++)
      af[mt] = *(const bf16x8*)(st + (wm + mt * 16 + l15) * 32 + ((quad ^ sk) * 8));
#pragma unroll
    for (int nt = 0; nt < 4; nt++)
      bg[nt] = *(const bf16x8*)(st + 4096 + (wn + nt * 16 + l15) * 32 + ((quad ^ sk) * 8));
#pragma unroll
    for (int mt = 0; mt < 4; mt++)
#pragma unroll
      for (int nt = 0; nt < 4; nt++)
        acc[mt][nt] = MFMA16(af[mt], bg[nt], acc[mt][nt]);
    asm volatile("s_barrier" ::: "memory");
    cs = (cs == 2) ? 0 : cs + 1;
    ls = (ls == 2) ? 0 : ls + 1;
  }
  __syncthreads();

  if (z == 2) {
    // transpose in LDS (col-major stride 136) then 16B coalesced stores to Vt[b,h,dk,s]
    u16* O = outp + z * 4194304;
#pragma unroll
    for (int mt = 0; mt < 4; mt++)
#pragma unroll
      for (int nt = 0; nt < 4; nt++) {
        int col = wn + nt * 16 + l15;
        int rowb = wm + mt * 16 + quad * 4;
        uint2 p;
        p.x = (u32)f2bf(acc[mt][nt][0]) | ((u32)f2bf(acc[mt][nt][1]) << 16);
        p.y = (u32)f2bf(acc[mt][nt][2]) | ((u32)f2bf(acc[mt][nt][3]) << 16);
        *(uint2*)(smem + col * 136 + rowb) = p;
      }
    __syncthreads();
    const int b = m0 >> 10, sbase = m0 & 1023;
#pragma unroll
    for (int p = 0; p < 8; p++) {
      int g = p * 256 + tid;
      int col = g >> 4, chunk = g & 15;
      uint4 v = *(const uint4*)(smem + col * 136 + chunk * 8);
      int nn = n0 + col, hh = nn >> 6, dk = nn & 63;
      *(uint4*)(O + ((b * 16 + hh) * 64 + dk) * 1024 + sbase + chunk * 8) = v;
    }
  } else {
    // retile [m][n] in LDS (stride 144) then 16B stores
    u16* O = outp + z * 4194304;
    const float scl = (z == 0) ? LOG2E : 1.0f;   // pre-scale Q for exp2-softmax
#pragma unroll
    for (int mt = 0; mt < 4; mt++)
#pragma unroll
      for (int nt = 0; nt < 4; nt++) {
        int rowb = wm + mt * 16 + quad * 4;
        int colb = wn + nt * 16 + l15;
#pragma unroll
        for (int reg = 0; reg < 4; reg++)
          smem[(rowb + reg) * 144 + colb] = f2bf(acc[mt][nt][reg] * scl);
      }
    __syncthreads();
    const int b = m0 >> 10, sbase = m0 & 1023;
#pragma unroll
    for (int p = 0; p < 8; p++) {
      int g = p * 256 + tid;
      int ml = g >> 4, c = g & 15;
      uint4 v = *(const uint4*)(smem + ml * 144 + c * 8);
      int nn = n0 + c * 8, hh = nn >> 6, dk = nn & 63;
      *(uint4*)(O + (b * 16 + hh) * 65536 + (sbase + ml) * 64 + dk) = v;
    }
  }
}

// ------- flash attention: (b,h) x 128 q-rows; 2-stage K/V async double-buffer -------
__global__ __launch_bounds__(256) void attn(const u16* __restrict__ Q, const u16* __restrict__ K,
                                            const u16* __restrict__ V, const float* __restrict__ emb,
                                            u16* __restrict__ ctx) {
  __shared__ __align__(16) u16 sKV[2 * 8192];   // stage: sK(4096 u16) + sV(4096 u16)
  __shared__ __align__(16) u16 sP[128 * 72];    // P [qrow][key], stride 72
  __shared__ __align__(16) float4 bt4[1156];    // replicated bias*log2e
  const int tid = threadIdx.x, lane = tid & 63, wave = tid >> 6;
  const int l15 = lane & 15, quad = lane >> 4;
  const int bh = blockIdx.x, qt = blockIdx.y;
  const int h = bh & 15, b = bh >> 4;
  const u16* Qp = Q + bh * 65536 + qt * 8192;
  const u16* Kp = K + bh * 65536;
  const u16* Vp = V + bh * 65536;
  const int sx = l15 & 7;

  int koff[2], voff[2], cbs[2];
#pragma unroll
  for (int r = 0; r < 2; r++) {
    int cb = r * 256 + wave * 64;
    int cc = cb + lane;
    int row = cc >> 3, c8 = (cc & 7) ^ (row & 7);
    koff[r] = row * 64 + c8 * 8;
    voff[r] = row * 1024 + c8 * 8;
    cbs[r] = cb * 8;
  }

  bf16x8 aq[2][2];
#pragma unroll
  for (int u = 0; u < 2; u++)
#pragma unroll
    for (int kk = 0; kk < 2; kk++)
      aq[u][kk] = *(const bf16x8*)(Qp + (wave * 32 + u * 16 + l15) * 64 + kk * 32 + quad * 8);

#pragma unroll
  for (int r = 0; r < 2; r++) {
    gld16(sKV + cbs[r], Kp + koff[r]);
    gld16(sKV + 4096 + cbs[r], Vp + voff[r]);
  }

  for (int i = tid; i < 1156; i += 256) {
    int rp0 = i - 127 - qt * 128;
    float4 v;
    v.x = emb[t5_bucket(rp0)     * 16 + h] * LOG2E;
    v.y = emb[t5_bucket(rp0 + 1) * 16 + h] * LOG2E;
    v.z = emb[t5_bucket(rp0 + 2) * 16 + h] * LOG2E;
    v.w = emb[t5_bucket(rp0 + 3) * 16 + h] * LOG2E;
    bt4[i] = v;
  }
  const float bias_pos = emb[31 * 16 + h] * LOG2E;  // rp >= 91
  const float bias_neg = emb[15 * 16 + h] * LOG2E;  // rp <= -91

  float2 ls2[2] = {{0.f, 0.f}, {0.f, 0.f}};
  f32x4 oc[2][4];
  const f32x4 vzero = {0.f, 0.f, 0.f, 0.f};
#pragma unroll
  for (int u = 0; u < 2; u++)
#pragma unroll
    for (int nt = 0; nt < 4; nt++) oc[u][nt] = vzero;

  __syncthreads();   // bt4 ready (also drains tile-0 loads — startup only)

#pragma unroll 1
  for (int j = 0; j < 16; j++) {
    u16* st = sKV + (j & 1) * 8192;
    if (j < 15) {
      u16* dst = sKV + ((j + 1) & 1) * 8192;
      const u16* Kj1 = Kp + (j + 1) * 4096;
      const u16* Vj1 = Vp + (j + 1) * 64;
#pragma unroll
      for (int r = 0; r < 2; r++) {
        gld16(dst + cbs[r], Kj1 + koff[r]);
        gld16(dst + 4096 + cbs[r], Vj1 + voff[r]);
      }
      asm volatile("s_waitcnt vmcnt(4)\n\ts_barrier" ::: "memory");
    } else {
      asm volatile("s_waitcnt vmcnt(0)\n\ts_barrier" ::: "memory");
    }

    f32x4 sc[4][2];
    const int rp_min = j * 64 - qt * 128 - 127;
    const int rp_max = j * 64 + 63 - qt * 128;
    if (rp_min >= 91) {
#pragma unroll
      for (int mt = 0; mt < 4; mt++)
#pragma unroll
        for (int u = 0; u < 2; u++) { sc[mt][u][0] = bias_pos; sc[mt][u][1] = bias_pos; sc[mt][u][2] = bias_pos; sc[mt][u][3] = bias_pos; }
    } else if (rp_max <= -91) {
#pragma unroll
      for (int mt = 0; mt < 4; mt++)
#pragma unroll
        for (int u = 0; u < 2; u++) { sc[mt][u][0] = bias_neg; sc[mt][u][1] = bias_neg; sc[mt][u][2] = bias_neg; sc[mt][u][3] = bias_neg; }
    } else {
#pragma unroll
      for (int mt = 0; mt < 4; mt++)
#pragma unroll
        for (int u = 0; u < 2; u++) {
          int idx = j * 64 + mt * 16 + quad * 4 - wave * 32 - u * 16 - l15 + 127;
          float4 bv4 = bt4[idx];
          sc[mt][u][0] = bv4.x; sc[mt][u][1] = bv4.y; sc[mt][u][2] = bv4.z; sc[mt][u][3] = bv4.w;
        }
    }
#pragma unroll
    for (int kk = 0; kk < 2; kk++) {
      bf16x8 ak[4];
      int g8 = kk * 4 + quad;
#pragma unroll
      for (int mt = 0; mt < 4; mt++)
        ak[mt] = *(const bf16x8*)(st + (mt * 16 + l15) * 64 + (g8 ^ sx) * 8);
#pragma unroll
      for (int mt = 0; mt < 4; mt++)
#pragma unroll
        for (int u = 0; u < 2; u++)
          sc[mt][u] = MFMA16(ak[mt], aq[u][kk], sc[mt][u]);
    }

#pragma unroll
    for (int u = 0; u < 2; u++) {
      const int prow = wave * 32 + u * 16 + l15;
#pragma unroll
      for (int mt = 0; mt < 4; mt++) {
        u32 b0 = __float_as_uint(__builtin_amdgcn_exp2f(sc[mt][u][0]));
        u32 b1 = __float_as_uint(__builtin_amdgcn_exp2f(sc[mt][u][1]));
        u32 b2 = __float_as_uint(__builtin_amdgcn_exp2f(sc[mt][u][2]));
        u32 b3 = __float_as_uint(__builtin_amdgcn_exp2f(sc[mt][u][3]));
        u32 t0 = b0 & 0xFFFF0000u, t1 = b1 & 0xFFFF0000u;
        u32 t2 = b2 & 0xFFFF0000u, t3 = b3 & 0xFFFF0000u;
        ls2[u].x += __uint_as_float(t0) + __uint_as_float(t2);
        ls2[u].y += __uint_as_float(t1) + __uint_as_float(t3);
        uint2 pk;
        pk.x = (t0 >> 16) | t1;
        pk.y = (t2 >> 16) | t3;
        *(uint2*)(sP + prow * 72 + mt * 16 + quad * 4) = pk;
      }
    }
    asm volatile("s_waitcnt lgkmcnt(0)" ::: "memory");   // wave-private P write->read

#pragma unroll
    for (int kk = 0; kk < 2; kk++) {
      bf16x8 ap[2];
      int g8 = kk * 4 + quad;
#pragma unroll
      for (int u = 0; u < 2; u++)
        ap[u] = *(const bf16x8*)(sP + (wave * 32 + u * 16 + l15) * 72 + kk * 32 + quad * 8);
#pragma unroll
      for (int nt = 0; nt < 4; nt++) {
        bf16x8 bv = *(const bf16x8*)(st + 4096 + (nt * 16 + l15) * 64 + (g8 ^ sx) * 8);
#pragma unroll
        for (int u = 0; u < 2; u++)
          oc[u][nt] = MFMA16(ap[u], bv, oc[u][nt]);
      }
    }
    asm volatile("s_barrier" ::: "memory");
  }

  float lsum[2];
#pragma unroll
  for (int u = 0; u < 2; u++) {
    lsum[u] = ls2[u].x + ls2[u].y;
    lsum[u] += __shfl_xor(lsum[u], 16, 64);
    lsum[u] += __shfl_xor(lsum[u], 32, 64);
  }
  float linv[2][4];
#pragma unroll
  for (int u = 0; u < 2; u++)
#pragma unroll
    for (int reg = 0; reg < 4; reg++)
      linv[u][reg] = __builtin_amdgcn_rcpf(__shfl(lsum[u], quad * 4 + reg, 64));

  u16* cb2 = ctx + b * 1048576 + (qt * 128 + wave * 32) * 1024 + h * 64;
#pragma unroll
  for (int u = 0; u < 2; u++)
#pragma unroll
    for (int nt = 0; nt < 4; nt++)
#pragma unroll
      for (int reg = 0; reg < 4; reg++)
        cb2[(u * 16 + quad * 4 + reg) * 1024 + nt * 16 + l15] = f2bf(oc[u][nt][reg] * linv[u][reg]);
}

// -------- out-proj GEMM: 64m x 128n tiles, 3-stage async pipeline, fp32 out --------
__global__ __launch_bounds__(256) void gemm_o(const u16* __restrict__ A,
                                              const u16* __restrict__ Bt,
                                              float* __restrict__ O) {
  __shared__ __align__(16) u16 smem[36864];   // 3 stages x (A 4096 + B 8192) u16 = 72 KB
  const int tid = threadIdx.x, lane = tid & 63, wave = tid >> 6;
  const int l15 = lane & 15, quad = lane >> 4;
  const int m0 = blockIdx.x * 64, n0 = blockIdx.y * 128;
  const u16* Ab = A + m0 * 1024;
  const u16* Bb = Bt + n0 * 1024;
  const int wn = wave * 32;

  int ar0 = tid >> 3, ar1 = (256 + tid) >> 3;
  int aoff0 = ar0 * 1024 + (((tid & 7) ^ (ar0 & 7)) * 8);
  int aoff1 = ar1 * 1024 + ((((256 + tid) & 7) ^ (ar1 & 7)) * 8);
  int boff[4], bdst[4];
#pragma unroll
  for (int r = 0; r < 4; r++) {
    int cc = r * 256 + tid;
    int row = cc >> 3;
    boff[r] = row * 1024 + (((cc & 7) ^ (row & 7)) * 8);
    bdst[r] = cc * 8;
  }

  f32x4 acc[4][2];
  const f32x4 vz = {0.f, 0.f, 0.f, 0.f};
#pragma unroll
  for (int i = 0; i < 4; i++) { acc[i][0] = vz; acc[i][1] = vz; }

  const int sx = l15 & 7;

#pragma unroll
  for (int s = 0; s < 2; s++) {
    u16* st = smem + s * 12288;
    const int ka = s * 64;
    gld16(st + tid * 8, Ab + ka + aoff0);
    gld16(st + (256 + tid) * 8, Ab + ka + aoff1);
#pragma unroll
    for (int r = 0; r < 4; r++) gld16(st + 4096 + bdst[r], Bb + ka + boff[r]);
  }

  int cs = 0, ls = 2;
#pragma unroll 1
  for (int kt = 0; kt < 16; kt++) {
    if (kt < 14) {
      u16* dst = smem + ls * 12288;
      const int ka = (kt + 2) * 64;
      gld16(dst + tid * 8, Ab + ka + aoff0);
      gld16(dst + (256 + tid) * 8, Ab + ka + aoff1);
#pragma unroll
      for (int r = 0; r < 4; r++) gld16(dst + 4096 + bdst[r], Bb + ka + boff[r]);
      asm volatile("s_waitcnt vmcnt(12)\n\ts_barrier" ::: "memory");
    } else if (kt == 14) {
      asm volatile("s_waitcnt vmcnt(6)\n\ts_barrier" ::: "memory");
    } else {
      asm volatile("s_waitcnt vmcnt(0)\n\ts_barrier" ::: "memory");
    }
    u16* st = smem + cs * 12288;
#pragma unroll
    for (int kk = 0; kk < 2; kk++) {
      bf16x8 af[4], bg[2];
      int g8 = kk * 4 + quad;
#pragma unroll
      for (int mt = 0; mt < 4; mt++)
        af[mt] = *(const bf16x8*)(st + (mt * 16 + l15) * 64 + ((g8 ^ sx) * 8));
#pragma unroll
      for (int nt = 0; nt < 2; nt++)
        bg[nt] = *(const bf16x8*)(st + 4096 + (wn + nt * 16 + l15) * 64 + ((g8 ^ sx) * 8));
#pragma unroll
      for (int mt = 0; mt < 4; mt++)
#pragma unroll
        for (int nt = 0; nt < 2; nt++)
          acc[mt][nt] = MFMA16(af[mt], bg[nt], acc[mt][nt]);
    }
    asm volatile("s_barrier" ::: "memory");
    cs = (cs == 2) ? 0 : cs + 1;
    ls = (ls == 2) ? 0 : ls + 1;
  }

#pragma unroll
  for (int mt = 0; mt < 4; mt++)
#pragma unroll
    for (int nt = 0; nt < 2; nt++)
#pragma unroll
      for (int reg = 0; reg < 4; reg++) {
        int row = m0 + mt * 16 + quad * 4 + reg;
        int col = n0 + wn + nt * 16 + l15;
        O[row * 1024 + col] = acc[mt][nt][reg];
      }
}

extern "C" void kernel_launch(void* const* d_in, const int* in_sizes, int n_in,
                              void* d_out, int out_size, void* d_ws, size_t ws_size,
                              hipStream_t stream) {
  (void)in_sizes; (void)n_in; (void)out_size; (void)ws_size;
  const float* X   = (const float*)d_in[0];
  const float* Wq  = (const float*)d_in[1];
  const float* Wk  = (const float*)d_in[2];
  const float* Wv  = (const float*)d_in[3];
  const float* Wo  = (const float*)d_in[4];
  const float* emb = (const float*)d_in[5];

  char* ws = (char*)d_ws;
  u16* Xb  = (u16*)(ws);                              // 8 MB: X bf16 [4096][1024]
  u16* Wt  = (u16*)(ws + (8u  << 20));                // 8 MB: Wq^T,Wk^T,Wv^T,Wo^T bf16
  u16* Qb  = (u16*)(ws + (16u << 20));                // 8+8+8 MB: Q(log2e-scaled), K, Vt
  u16* Ctx = (u16*)(ws + (40u << 20));                // 8 MB: attention output bf16

  prep<<<1024, 256, 0, stream>>>((const float4*)X, (ushort4*)Xb, Wq, Wk, Wv, Wo, Wt);
  gemm128<<<dim3(24, 32), 256, 0, stream>>>(Xb, Wt, Qb);
  attn<<<dim3(64, 8), 256, 0, stream>>>(Qb, Qb + 4194304, Qb + 2 * 4194304, emb, Ctx);
  gemm_o<<<dim3(64, 8), 256, 0, stream>>>(Ctx, Wt + 3 * 1048576, (float*)d_out);
}